// Round 13
// baseline (268.446 us; speedup 1.0000x reference)
//
#include <hip/hip_runtime.h>
#include <stdint.h>

#define M_DIM 8192
#define N_DIM 4096
#define K_DIM 4096
#define NT (K_DIM / 128)  // 32 k-tiles of 128 fp8 bytes

typedef float f32x4 __attribute__((ext_vector_type(4)));
typedef float f32x16 __attribute__((ext_vector_type(16)));
typedef int v4i __attribute__((ext_vector_type(4)));
typedef int v8i __attribute__((ext_vector_type(8)));
typedef uint32_t u32;

// ---------- helpers ----------

__device__ __forceinline__ void gload_lds16(const void* g, void* l) {
  __builtin_amdgcn_global_load_lds(
      (__attribute__((address_space(1))) void*)(g),
      (__attribute__((address_space(3))) void*)(l), 16, 0, 0);
}

__device__ __forceinline__ float clipmul(float v, float rs) {
  v = v * rs;
  return fminf(fmaxf(v, -448.f), 448.f);
}

__device__ __forceinline__ u32 pack4_fp8(float a, float b, float c, float d) {
  int w = __builtin_amdgcn_cvt_pk_fp8_f32(a, b, 0, false);
  w = __builtin_amdgcn_cvt_pk_fp8_f32(c, d, w, true);
  return (u32)w;
}

__device__ __forceinline__ v8i rd8(const void* lo, const void* hi) {
  v4i l = *(const v4i*)lo;
  v4i h = *(const v4i*)hi;
  return __builtin_shufflevector(l, h, 0, 1, 2, 3, 4, 5, 6, 7);
}

__device__ __forceinline__ f32x16 mfma32(v8i a, v8i b, f32x16 c) {
  return __builtin_amdgcn_mfma_scale_f32_32x32x64_f8f6f4(
      a, b, c, 0, 0, 0, 0x7f7f7f7f, 0, 0x7f7f7f7f);
}

// ---------- quantize A (row-major M x K, f32 -> e4m3fn) ----------

__global__ __launch_bounds__(256) void quant_a(const float* __restrict__ x,
                                               u32* __restrict__ q,
                                               const float* __restrict__ scale,
                                               int nv4) {
  int base = blockIdx.x * 1024 + threadIdx.x;
  float rs = 1.0f / scale[0];
#pragma unroll
  for (int r = 0; r < 4; ++r) {
    int idx = base + r * 256;
    if (idx < nv4) {
      float4 v = ((const float4*)x)[idx];
      q[idx] = pack4_fp8(clipmul(v.x, rs), clipmul(v.y, rs),
                         clipmul(v.z, rs), clipmul(v.w, rs));
    }
  }
}

// ---------- quantize + transpose B (K x N f32 -> N x K fp8), u32-packed ----

__global__ __launch_bounds__(256) void quant_b_t(const float* __restrict__ B,
                                                 uint8_t* __restrict__ qT,
                                                 const float* __restrict__ scale) {
  __shared__ u32 lt[64 * 17];  // 64 n-rows x 16 dwords + 1 pad
  int tid = threadIdx.x;
  int kt = blockIdx.x * 64;
  int nt = blockIdx.y * 64;
  float rs = 1.0f / scale[0];

  int kq = tid >> 4;  // 0..15 -> k0 = 4*kq
  int nq = tid & 15;  // 0..15 -> n0 = 4*nq
  int k0 = kq * 4, n0 = nq * 4;
  const float* src = B + (long)(kt + k0) * N_DIM + nt + n0;
  float4 v0 = *(const float4*)(src);
  float4 v1 = *(const float4*)(src + N_DIM);
  float4 v2 = *(const float4*)(src + 2 * N_DIM);
  float4 v3 = *(const float4*)(src + 3 * N_DIM);

  lt[(n0 + 0) * 17 + kq] = pack4_fp8(clipmul(v0.x, rs), clipmul(v1.x, rs),
                                     clipmul(v2.x, rs), clipmul(v3.x, rs));
  lt[(n0 + 1) * 17 + kq] = pack4_fp8(clipmul(v0.y, rs), clipmul(v1.y, rs),
                                     clipmul(v2.y, rs), clipmul(v3.y, rs));
  lt[(n0 + 2) * 17 + kq] = pack4_fp8(clipmul(v0.z, rs), clipmul(v1.z, rs),
                                     clipmul(v2.z, rs), clipmul(v3.z, rs));
  lt[(n0 + 3) * 17 + kq] = pack4_fp8(clipmul(v0.w, rs), clipmul(v1.w, rs),
                                     clipmul(v2.w, rs), clipmul(v3.w, rs));
  __syncthreads();

  int n = tid >> 2, ch = tid & 3;
  uint4 o;
  o.x = lt[n * 17 + ch * 4 + 0];
  o.y = lt[n * 17 + ch * 4 + 1];
  o.z = lt[n * 17 + ch * 4 + 2];
  o.w = lt[n * 17 + ch * 4 + 3];
  *(uint4*)&qT[(long)(nt + n) * K_DIM + kt + ch * 16] = o;
}

// ---------- 256x256 MX-fp8 GEMM, 32x32x64, A-in-LDS, B-in-regs ----------
// r9's winning coarse schedule (134.8 us) with B taken out of LDS:
// B fragments load DIRECTLY from global into registers, double-buffered one
// K-tile ahead (load B(t+1) at the start of tile t; the tile-end vmcnt(0) —
// already required for A staging — guarantees completion; latency hides
// under the whole tile's compute). This removes 64 of 192 LDS reads and
// half the LDS stage-writes per CU per K-tile: LDS serial (~2290 cy) now
// matches the MFMA pipe (~2200 cy) instead of dominating it (r9: ~3590).
// r8's failure mode (B consumed same-phase as loaded -> exposed latency)
// is avoided by the one-tile-ahead prefetch. B named ping/pong arrays
// (rule #20: no runtime-indexed ext_vector arrays).
// LDS 64 KiB: A bufs [0,32K),[32K,64K). A swizzle identical to r9.
// WAR: stage targets buf^1; reads of buf retire before each wave's MFMAs
// hence before the barrier. Register WAR on b arrays is compiler-managed.
// RAW: vmcnt(0) before the barrier covers both A-stage and B-prefetch.

template <int BUF>
__device__ __forceinline__ void stage_a(const uint8_t* const (&gA)[4],
                                        uint8_t* lds, const int (&ldo)[4],
                                        long ko) {
#pragma unroll
  for (int r = 0; r < 4; ++r)
    gload_lds16(gA[r] + ko, lds + BUF * 32768 + ldo[r]);
}

// b[ks*2+nj]: fragment for k-slice ks, col-block nj
__device__ __forceinline__ void load_b(v8i (&b)[4],
                                       const uint8_t* const (&pB)[2], long ko) {
#pragma unroll
  for (int ks = 0; ks < 2; ++ks)
#pragma unroll
    for (int nj = 0; nj < 2; ++nj) {
      const uint8_t* p = pB[nj] + ko + ks * 64;
      b[ks * 2 + nj] = rd8(p, p + 16);
    }
}

template <int BUF>
__device__ __forceinline__ void compute_tile(const uint8_t* lds,
                                             const int (&offA)[4][4],
                                             const v8i (&b)[4],
                                             f32x16 (&acc)[4][2]) {
  const uint8_t* Ab = lds + BUF * 32768;
#pragma unroll
  for (int ks = 0; ks < 2; ++ks) {
    v8i a[4];
#pragma unroll
    for (int mi = 0; mi < 4; ++mi)
      a[mi] = rd8(Ab + offA[mi][ks * 2], Ab + offA[mi][ks * 2 + 1]);
#pragma unroll
    for (int mi = 0; mi < 4; ++mi)
#pragma unroll
      for (int nj = 0; nj < 2; ++nj)
        acc[mi][nj] = mfma32(a[mi], b[ks * 2 + nj], acc[mi][nj]);
  }
}

__global__ __launch_bounds__(512, 2) void gemm_mx(const uint8_t* __restrict__ Aq,
                                                  const uint8_t* __restrict__ BqT,
                                                  float* __restrict__ C,
                                                  const float* __restrict__ sA,
                                                  const float* __restrict__ sB) {
  __shared__ __align__(16) uint8_t lds[65536];  // A only: 2 bufs x 32 KB

  const int tid = threadIdx.x;
  const int lane = tid & 63;
  const int wid = tid >> 6;
  const int wr = wid >> 2;  // 0..1: 128-row strip of A
  const int wc = wid & 3;   // 0..3: 64-col strip of B
  const int l31 = lane & 31;
  const int hi2 = lane >> 5;  // 0..1

  // XCD-aware swizzle: 512 wgs, 64 per XCD chunk (bijective, 512%8==0)
  int bid = blockIdx.x;
  int wg = (bid & 7) * 64 + (bid >> 3);
  const long bm = (long)(wg >> 4) * 256;  // 32 M-tiles
  const long bn = (long)(wg & 15) * 256;  // 16 N-tiles

  // scales: materialize before staging so their loads never sit in the vmem
  // queue during the counted waits.
  float s = sA[0] * sB[0];
  asm volatile("" ::"v"(s));

  // --- A staging: 2048 granules, 4 per thread, pre-swizzled source ---
  const uint8_t* gA[4];
  int ldo[4];
#pragma unroll
  for (int r = 0; r < 4; ++r) {
    int gid = tid + 512 * r;
    int row = gid >> 3, gc = gid & 7;
    int sc = (gc ^ (row & 7)) << 4;  // pre-swizzled source granule
    gA[r] = Aq + (bm + row) * (long)K_DIM + sc;
    ldo[r] = gid * 16;  // linear LDS dest
  }

  // --- A fragment read offsets (loop-invariant, swizzled) ---
  int offA[4][4];
#pragma unroll
  for (int mi = 0; mi < 4; ++mi) {
    int ra = wr * 128 + mi * 32 + l31;  // 0..255
#pragma unroll
    for (int ks = 0; ks < 2; ++ks)
#pragma unroll
      for (int j = 0; j < 2; ++j) {
        int g = ks * 4 + hi2 * 2 + j;
        offA[mi][ks * 2 + j] = ra * 128 + ((g ^ (ra & 7)) << 4);
      }
  }

  // --- B fragment global base pointers (per lane, 32 contiguous bytes) ---
  const uint8_t* pB[2];
#pragma unroll
  for (int nj = 0; nj < 2; ++nj) {
    long rb = bn + wc * 64 + nj * 32 + l31;
    pB[nj] = BqT + rb * (long)K_DIM + hi2 * 32;
  }

  f32x16 acc[4][2] = {};
  v8i b_even[4], b_odd[4];

  // ---- prologue: stage A(0), prefetch B(0); drain ----
  stage_a<0>(gA, lds, ldo, 0);
  load_b(b_even, pB, 0);
  asm volatile("s_waitcnt vmcnt(0)" ::: "memory");
  __builtin_amdgcn_s_barrier();

  // ---- main loop: 2 K-tiles per iteration, static buffers ----
  for (int i = 0; i < NT / 2; ++i) {
    {  // tile 2i: A from buf0, B from b_even; prefetch tile 2i+1
      long ko1 = (long)((2 * i + 1) & (NT - 1)) * 128;
      load_b(b_odd, pB, ko1);          // 8 vmem -> regs (oldest in queue)
      stage_a<1>(gA, lds, ldo, ko1);   // 4 gload_lds
      compute_tile<0>(lds, offA, b_even, acc);
      asm volatile("s_waitcnt vmcnt(0)" ::: "memory");
      __builtin_amdgcn_s_barrier();
    }
    {  // tile 2i+1: A from buf1, B from b_odd; prefetch tile 2i+2
      long ko2 = (long)((2 * i + 2) & (NT - 1)) * 128;  // wraps harmlessly
      load_b(b_even, pB, ko2);
      stage_a<0>(gA, lds, ldo, ko2);
      compute_tile<1>(lds, offA, b_odd, acc);
      asm volatile("s_waitcnt vmcnt(0)" ::: "memory");
      __builtin_amdgcn_s_barrier();
    }
  }

  // ---- epilogue: C-write (32x32 C/D layout) ----
#pragma unroll
  for (int mi = 0; mi < 4; ++mi)
#pragma unroll
    for (int nj = 0; nj < 2; ++nj) {
      f32x16 v = acc[mi][nj];
      long col = bn + wc * 64 + nj * 32 + l31;
#pragma unroll
      for (int q = 0; q < 16; ++q) {
        long row = bm + wr * 128 + mi * 32 + (q & 3) + 8 * (q >> 2) + 4 * hi2;
        C[row * N_DIM + col] = v[q] * s;
      }
    }
}

// ---------- launcher ----------

extern "C" void kernel_launch(void* const* d_in, const int* in_sizes, int n_in,
                              void* d_out, int out_size, void* d_ws, size_t ws_size,
                              hipStream_t stream) {
  const float* A = (const float*)d_in[0];   // (8192, 4096)
  const float* B = (const float*)d_in[1];   // (4096, 4096)
  const float* sA = (const float*)d_in[2];  // input_scale
  const float* sB = (const float*)d_in[4];  // kernel_scale
  float* out = (float*)d_out;

  uint8_t* Aq = (uint8_t*)d_ws;               // M*K fp8
  uint8_t* BqT = Aq + (size_t)M_DIM * K_DIM;  // N*K fp8 (transposed)

  int nv4_a = M_DIM * K_DIM / 4;
  quant_a<<<nv4_a / 1024, 256, 0, stream>>>(A, (u32*)Aq, sA, nv4_a);
  quant_b_t<<<dim3(K_DIM / 64, N_DIM / 64), 256, 0, stream>>>(B, BqT, sB);
  gemm_mx<<<dim3((M_DIM / 256) * (N_DIM / 256)), 512, 0, stream>>>(Aq, BqT, out, sA, sB);
}

// Round 14
// 188.687 us; speedup vs baseline: 1.4227x; 1.4227x over previous
//
#include <hip/hip_runtime.h>
#include <stdint.h>

#define M_DIM 8192
#define N_DIM 4096
#define K_DIM 4096
#define NT (K_DIM / 128)  // 32 k-tiles of 128 fp8 bytes

typedef float f32x4 __attribute__((ext_vector_type(4)));
typedef float f32x16 __attribute__((ext_vector_type(16)));
typedef int v4i __attribute__((ext_vector_type(4)));
typedef int v8i __attribute__((ext_vector_type(8)));
typedef uint32_t u32;

// ---------- helpers ----------

__device__ __forceinline__ void gload_lds16(const void* g, void* l) {
  __builtin_amdgcn_global_load_lds(
      (__attribute__((address_space(1))) void*)(g),
      (__attribute__((address_space(3))) void*)(l), 16, 0, 0);
}

__device__ __forceinline__ float clipmul(float v, float rs) {
  v = v * rs;
  return fminf(fmaxf(v, -448.f), 448.f);
}

__device__ __forceinline__ u32 pack4_fp8(float a, float b, float c, float d) {
  int w = __builtin_amdgcn_cvt_pk_fp8_f32(a, b, 0, false);
  w = __builtin_amdgcn_cvt_pk_fp8_f32(c, d, w, true);
  return (u32)w;
}

__device__ __forceinline__ v8i rd8(const void* lo, const void* hi) {
  v4i l = *(const v4i*)lo;
  v4i h = *(const v4i*)hi;
  return __builtin_shufflevector(l, h, 0, 1, 2, 3, 4, 5, 6, 7);
}

__device__ __forceinline__ f32x16 mfma32(v8i a, v8i b, f32x16 c) {
  return __builtin_amdgcn_mfma_scale_f32_32x32x64_f8f6f4(
      a, b, c, 0, 0, 0, 0x7f7f7f7f, 0, 0x7f7f7f7f);
}

// ---------- quantize A (row-major M x K, f32 -> e4m3fn) ----------
// clipmul (hoisted reciprocal) per r10/r12: ~41.5us for both quants vs 54us
// with per-element v_div.

__global__ __launch_bounds__(256) void quant_a(const float* __restrict__ x,
                                               u32* __restrict__ q,
                                               const float* __restrict__ scale,
                                               int nv4) {
  int base = blockIdx.x * 1024 + threadIdx.x;
  float rs = 1.0f / scale[0];
#pragma unroll
  for (int r = 0; r < 4; ++r) {
    int idx = base + r * 256;
    if (idx < nv4) {
      float4 v = ((const float4*)x)[idx];
      q[idx] = pack4_fp8(clipmul(v.x, rs), clipmul(v.y, rs),
                         clipmul(v.z, rs), clipmul(v.w, rs));
    }
  }
}

// ---------- quantize + transpose B (K x N f32 -> N x K fp8), u32-packed ----

__global__ __launch_bounds__(256) void quant_b_t(const float* __restrict__ B,
                                                 uint8_t* __restrict__ qT,
                                                 const float* __restrict__ scale) {
  __shared__ u32 lt[64 * 17];  // 64 n-rows x 16 dwords + 1 pad
  int tid = threadIdx.x;
  int kt = blockIdx.x * 64;
  int nt = blockIdx.y * 64;
  float rs = 1.0f / scale[0];

  int kq = tid >> 4;  // 0..15 -> k0 = 4*kq
  int nq = tid & 15;  // 0..15 -> n0 = 4*nq
  int k0 = kq * 4, n0 = nq * 4;
  const float* src = B + (long)(kt + k0) * N_DIM + nt + n0;
  float4 v0 = *(const float4*)(src);
  float4 v1 = *(const float4*)(src + N_DIM);
  float4 v2 = *(const float4*)(src + 2 * N_DIM);
  float4 v3 = *(const float4*)(src + 3 * N_DIM);

  lt[(n0 + 0) * 17 + kq] = pack4_fp8(clipmul(v0.x, rs), clipmul(v1.x, rs),
                                     clipmul(v2.x, rs), clipmul(v3.x, rs));
  lt[(n0 + 1) * 17 + kq] = pack4_fp8(clipmul(v0.y, rs), clipmul(v1.y, rs),
                                     clipmul(v2.y, rs), clipmul(v3.y, rs));
  lt[(n0 + 2) * 17 + kq] = pack4_fp8(clipmul(v0.z, rs), clipmul(v1.z, rs),
                                     clipmul(v2.z, rs), clipmul(v3.z, rs));
  lt[(n0 + 3) * 17 + kq] = pack4_fp8(clipmul(v0.w, rs), clipmul(v1.w, rs),
                                     clipmul(v2.w, rs), clipmul(v3.w, rs));
  __syncthreads();

  int n = tid >> 2, ch = tid & 3;
  uint4 o;
  o.x = lt[n * 17 + ch * 4 + 0];
  o.y = lt[n * 17 + ch * 4 + 1];
  o.z = lt[n * 17 + ch * 4 + 2];
  o.w = lt[n * 17 + ch * 4 + 3];
  *(uint4*)&qT[(long)(nt + n) * K_DIM + kt + ch * 16] = o;
}

// ---------- 256x256 MX-fp8 GEMM, 32x32x64, coarse 2-phase (r9 exact) ----------
// The round-9 winner, byte-for-byte: 8 waves (2M x 4N), wave tile 128x64,
// BK=128, 24 ds_read_b128 + 16 mfma32 per wave per K-tile, double-buffered
// 128 KiB LDS, stage(buf^1,t+1) issued first, single vmcnt(0)+barrier per
// K-tile. Best of 7 structural variants tested (134.8 us, 2040 TF).
// Granule swizzle g^(row&7) applied pre-swizzled-source + swizzled-read.

template <int BUF>
__device__ __forceinline__ void stage_tile(const uint8_t* const (&gA)[4],
                                           const uint8_t* const (&gB)[4],
                                           uint8_t* lds, const int (&ldo)[4],
                                           long ko) {
#pragma unroll
  for (int r = 0; r < 4; ++r)
    gload_lds16(gA[r] + ko, lds + BUF * 32768 + ldo[r]);
#pragma unroll
  for (int r = 0; r < 4; ++r)
    gload_lds16(gB[r] + ko, lds + 65536 + BUF * 32768 + ldo[r]);
}

template <int BUF>
__device__ __forceinline__ void compute_tile(const uint8_t* lds,
                                             const int (&offA)[4][4],
                                             const int (&offB)[2][4],
                                             f32x16 (&acc)[4][2]) {
  const uint8_t* Ab = lds + BUF * 32768;
  const uint8_t* Bb = lds + 65536 + BUF * 32768;
#pragma unroll
  for (int ks = 0; ks < 2; ++ks) {
    v8i b[2], a[4];
#pragma unroll
    for (int nj = 0; nj < 2; ++nj)
      b[nj] = rd8(Bb + offB[nj][ks * 2], Bb + offB[nj][ks * 2 + 1]);
#pragma unroll
    for (int mi = 0; mi < 4; ++mi)
      a[mi] = rd8(Ab + offA[mi][ks * 2], Ab + offA[mi][ks * 2 + 1]);
#pragma unroll
    for (int mi = 0; mi < 4; ++mi)
#pragma unroll
      for (int nj = 0; nj < 2; ++nj)
        acc[mi][nj] = mfma32(a[mi], b[nj], acc[mi][nj]);
  }
}

__global__ __launch_bounds__(512, 2) void gemm_mx(const uint8_t* __restrict__ Aq,
                                                  const uint8_t* __restrict__ BqT,
                                                  float* __restrict__ C,
                                                  const float* __restrict__ sA,
                                                  const float* __restrict__ sB) {
  __shared__ __align__(16) uint8_t lds[131072];

  const int tid = threadIdx.x;
  const int lane = tid & 63;
  const int wid = tid >> 6;
  const int wr = wid >> 2;  // 0..1: 128-row strip of A
  const int wc = wid & 3;   // 0..3: 64-col strip of B
  const int l31 = lane & 31;
  const int hi2 = lane >> 5;  // 0..1

  // XCD-aware swizzle: 512 wgs, 64 per XCD chunk (bijective, 512%8==0)
  int bid = blockIdx.x;
  int wg = (bid & 7) * 64 + (bid >> 3);
  const long bm = (long)(wg >> 4) * 256;  // 32 M-tiles
  const long bn = (long)(wg & 15) * 256;  // 16 N-tiles

  // scales: materialize before staging so their loads never sit in the vmem
  // queue during the counted waits.
  float s = sA[0] * sB[0];
  asm volatile("" ::"v"(s));

  // --- staging: 2048 granules per matrix, 4 per thread, pre-swizzled src ---
  const uint8_t* gA[4];
  const uint8_t* gB[4];
  int ldo[4];
#pragma unroll
  for (int r = 0; r < 4; ++r) {
    int gid = tid + 512 * r;
    int row = gid >> 3, gc = gid & 7;
    int sc = (gc ^ (row & 7)) << 4;  // pre-swizzled source granule
    gA[r] = Aq + (bm + row) * (long)K_DIM + sc;
    gB[r] = BqT + (bn + row) * (long)K_DIM + sc;
    ldo[r] = gid * 16;  // linear LDS dest
  }

  // --- fragment read offsets (loop-invariant, swizzled) ---
  int offA[4][4], offB[2][4];
#pragma unroll
  for (int mi = 0; mi < 4; ++mi) {
    int ra = wr * 128 + mi * 32 + l31;  // 0..255
#pragma unroll
    for (int ks = 0; ks < 2; ++ks)
#pragma unroll
      for (int j = 0; j < 2; ++j) {
        int g = ks * 4 + hi2 * 2 + j;
        offA[mi][ks * 2 + j] = ra * 128 + ((g ^ (ra & 7)) << 4);
      }
  }
#pragma unroll
  for (int nj = 0; nj < 2; ++nj) {
    int rb = wc * 64 + nj * 32 + l31;  // 0..255
#pragma unroll
    for (int ks = 0; ks < 2; ++ks)
#pragma unroll
      for (int j = 0; j < 2; ++j) {
        int g = ks * 4 + hi2 * 2 + j;
        offB[nj][ks * 2 + j] = rb * 128 + ((g ^ (rb & 7)) << 4);
      }
  }

  f32x16 acc[4][2] = {};

  // ---- prologue ----
  stage_tile<0>(gA, gB, lds, ldo, 0);
  asm volatile("s_waitcnt vmcnt(0)" ::: "memory");
  __builtin_amdgcn_s_barrier();

  // ---- main loop: 2 K-tiles per iteration, static buffer indices ----
  for (int i = 0; i < NT / 2; ++i) {
    long ko1 = (long)((2 * i + 1) & (NT - 1)) * 128;
    stage_tile<1>(gA, gB, lds, ldo, ko1);   // issue first
    compute_tile<0>(lds, offA, offB, acc);  // 24 reads + 16 MFMA per wave
    asm volatile("s_waitcnt vmcnt(0)" ::: "memory");
    __builtin_amdgcn_s_barrier();

    long ko2 = (long)((2 * i + 2) & (NT - 1)) * 128;  // wraps harmlessly
    stage_tile<0>(gA, gB, lds, ldo, ko2);
    compute_tile<1>(lds, offA, offB, acc);
    asm volatile("s_waitcnt vmcnt(0)" ::: "memory");
    __builtin_amdgcn_s_barrier();
  }

  // ---- epilogue: C-write (32x32 C/D layout) ----
#pragma unroll
  for (int mi = 0; mi < 4; ++mi)
#pragma unroll
    for (int nj = 0; nj < 2; ++nj) {
      f32x16 v = acc[mi][nj];
      long col = bn + wc * 64 + nj * 32 + l31;
#pragma unroll
      for (int q = 0; q < 16; ++q) {
        long row = bm + wr * 128 + mi * 32 + (q & 3) + 8 * (q >> 2) + 4 * hi2;
        C[row * N_DIM + col] = v[q] * s;
      }
    }
}

// ---------- launcher ----------

extern "C" void kernel_launch(void* const* d_in, const int* in_sizes, int n_in,
                              void* d_out, int out_size, void* d_ws, size_t ws_size,
                              hipStream_t stream) {
  const float* A = (const float*)d_in[0];   // (8192, 4096)
  const float* B = (const float*)d_in[1];   // (4096, 4096)
  const float* sA = (const float*)d_in[2];  // input_scale
  const float* sB = (const float*)d_in[4];  // kernel_scale
  float* out = (float*)d_out;

  uint8_t* Aq = (uint8_t*)d_ws;               // M*K fp8
  uint8_t* BqT = Aq + (size_t)M_DIM * K_DIM;  // N*K fp8 (transposed)

  int nv4_a = M_DIM * K_DIM / 4;
  quant_a<<<nv4_a / 1024, 256, 0, stream>>>(A, (u32*)Aq, sA, nv4_a);
  quant_b_t<<<dim3(K_DIM / 64, N_DIM / 64), 256, 0, stream>>>(B, BqT, sB);
  gemm_mx<<<dim3((M_DIM / 256) * (N_DIM / 256)), 512, 0, stream>>>(Aq, BqT, out, sA, sB);
}

// Round 15
// 187.195 us; speedup vs baseline: 1.4340x; 1.0080x over previous
//
#include <hip/hip_runtime.h>
#include <stdint.h>

#define M_DIM 8192
#define N_DIM 4096
#define K_DIM 4096
#define NT (K_DIM / 128)  // 32 k-tiles of 128 fp8 bytes

typedef float f32x4 __attribute__((ext_vector_type(4)));
typedef float f32x16 __attribute__((ext_vector_type(16)));
typedef int v4i __attribute__((ext_vector_type(4)));
typedef int v8i __attribute__((ext_vector_type(8)));
typedef uint32_t u32;

// ---------- helpers ----------

__device__ __forceinline__ void gload_lds16(const void* g, void* l) {
  __builtin_amdgcn_global_load_lds(
      (__attribute__((address_space(1))) void*)(g),
      (__attribute__((address_space(3))) void*)(l), 16, 0, 0);
}

__device__ __forceinline__ float clipmul(float v, float rs) {
  v = v * rs;
  return fminf(fmaxf(v, -448.f), 448.f);
}

__device__ __forceinline__ u32 pack4_fp8(float a, float b, float c, float d) {
  int w = __builtin_amdgcn_cvt_pk_fp8_f32(a, b, 0, false);
  w = __builtin_amdgcn_cvt_pk_fp8_f32(c, d, w, true);
  return (u32)w;
}

__device__ __forceinline__ v8i rd8(const void* lo, const void* hi) {
  v4i l = *(const v4i*)lo;
  v4i h = *(const v4i*)hi;
  return __builtin_shufflevector(l, h, 0, 1, 2, 3, 4, 5, 6, 7);
}

__device__ __forceinline__ f32x16 mfma32(v8i a, v8i b, f32x16 c) {
  return __builtin_amdgcn_mfma_scale_f32_32x32x64_f8f6f4(
      a, b, c, 0, 0, 0, 0x7f7f7f7f, 0, 0x7f7f7f7f);
}

// ---------- fused quantize: A (elementwise) + B (transpose), one dispatch ----
// Blocks [0, NA_BLK): quantize A (row-major M x K f32 -> e4m3fn), 1024 v4/blk.
// Blocks [NA_BLK, NA_BLK+NB_BLK): quantize+transpose a 64x64 tile of B.
// Bodies are byte-identical to the r10/r12-proven kernels; fusing removes one
// graph-node boundary (device drain + relaunch) and fills the A-pass tail.

#define NA_BLK (M_DIM * K_DIM / 4 / 1024)           // 8192
#define NB_BLK ((K_DIM / 64) * (N_DIM / 64))        // 4096

__global__ __launch_bounds__(256) void quant_fused(
    const float* __restrict__ A, const float* __restrict__ B,
    u32* __restrict__ qA, uint8_t* __restrict__ qBT,
    const float* __restrict__ sA, const float* __restrict__ sB) {
  __shared__ u32 lt[64 * 17];  // used by B-blocks only (64 n-rows x 16+1 dw)
  int bid = blockIdx.x;
  int tid = threadIdx.x;

  if (bid < NA_BLK) {
    // ---- A part ----
    int base = bid * 1024 + tid;
    float rs = 1.0f / sA[0];
#pragma unroll
    for (int r = 0; r < 4; ++r) {
      int idx = base + r * 256;
      float4 v = ((const float4*)A)[idx];
      qA[idx] = pack4_fp8(clipmul(v.x, rs), clipmul(v.y, rs),
                          clipmul(v.z, rs), clipmul(v.w, rs));
    }
    return;
  }

  // ---- B part: 64x64 tile transpose-quantize ----
  int bt = bid - NA_BLK;
  int kt = (bt & (K_DIM / 64 - 1)) * 64;  // 64 k-tiles
  int nt = (bt / (K_DIM / 64)) * 64;
  float rs = 1.0f / sB[0];

  int kq = tid >> 4;  // 0..15 -> k0 = 4*kq
  int nq = tid & 15;  // 0..15 -> n0 = 4*nq
  int k0 = kq * 4, n0 = nq * 4;
  const float* src = B + (long)(kt + k0) * N_DIM + nt + n0;
  float4 v0 = *(const float4*)(src);
  float4 v1 = *(const float4*)(src + N_DIM);
  float4 v2 = *(const float4*)(src + 2 * N_DIM);
  float4 v3 = *(const float4*)(src + 3 * N_DIM);

  lt[(n0 + 0) * 17 + kq] = pack4_fp8(clipmul(v0.x, rs), clipmul(v1.x, rs),
                                     clipmul(v2.x, rs), clipmul(v3.x, rs));
  lt[(n0 + 1) * 17 + kq] = pack4_fp8(clipmul(v0.y, rs), clipmul(v1.y, rs),
                                     clipmul(v2.y, rs), clipmul(v3.y, rs));
  lt[(n0 + 2) * 17 + kq] = pack4_fp8(clipmul(v0.z, rs), clipmul(v1.z, rs),
                                     clipmul(v2.z, rs), clipmul(v3.z, rs));
  lt[(n0 + 3) * 17 + kq] = pack4_fp8(clipmul(v0.w, rs), clipmul(v1.w, rs),
                                     clipmul(v2.w, rs), clipmul(v3.w, rs));
  __syncthreads();

  int n = tid >> 2, ch = tid & 3;
  uint4 o;
  o.x = lt[n * 17 + ch * 4 + 0];
  o.y = lt[n * 17 + ch * 4 + 1];
  o.z = lt[n * 17 + ch * 4 + 2];
  o.w = lt[n * 17 + ch * 4 + 3];
  *(uint4*)&qBT[(long)(nt + n) * K_DIM + kt + ch * 16] = o;
}

// ---------- 256x256 MX-fp8 GEMM, 32x32x64, coarse 2-phase (r9 exact) ----------
// The round-9 winner, byte-for-byte: 8 waves (2M x 4N), wave tile 128x64,
// BK=128, 24 ds_read_b128 + 16 mfma32 per wave per K-tile, double-buffered
// 128 KiB LDS, stage(buf^1,t+1) issued first, single vmcnt(0)+barrier per
// K-tile. Best of 8 structural variants tested (134.2-134.8 us, ~2040 TF).
// Granule swizzle g^(row&7): pre-swizzled source + swizzled read (rule #21);
// spreads each ds_read_b128 uniformly 8 lanes/bank over all 32 banks (the
// 64-lane x 16B minimum) — bank-optimal for this fragment layout.

template <int BUF>
__device__ __forceinline__ void stage_tile(const uint8_t* const (&gA)[4],
                                           const uint8_t* const (&gB)[4],
                                           uint8_t* lds, const int (&ldo)[4],
                                           long ko) {
#pragma unroll
  for (int r = 0; r < 4; ++r)
    gload_lds16(gA[r] + ko, lds + BUF * 32768 + ldo[r]);
#pragma unroll
  for (int r = 0; r < 4; ++r)
    gload_lds16(gB[r] + ko, lds + 65536 + BUF * 32768 + ldo[r]);
}

template <int BUF>
__device__ __forceinline__ void compute_tile(const uint8_t* lds,
                                             const int (&offA)[4][4],
                                             const int (&offB)[2][4],
                                             f32x16 (&acc)[4][2]) {
  const uint8_t* Ab = lds + BUF * 32768;
  const uint8_t* Bb = lds + 65536 + BUF * 32768;
#pragma unroll
  for (int ks = 0; ks < 2; ++ks) {
    v8i b[2], a[4];
#pragma unroll
    for (int nj = 0; nj < 2; ++nj)
      b[nj] = rd8(Bb + offB[nj][ks * 2], Bb + offB[nj][ks * 2 + 1]);
#pragma unroll
    for (int mi = 0; mi < 4; ++mi)
      a[mi] = rd8(Ab + offA[mi][ks * 2], Ab + offA[mi][ks * 2 + 1]);
#pragma unroll
    for (int mi = 0; mi < 4; ++mi)
#pragma unroll
      for (int nj = 0; nj < 2; ++nj)
        acc[mi][nj] = mfma32(a[mi], b[nj], acc[mi][nj]);
  }
}

__global__ __launch_bounds__(512, 2) void gemm_mx(const uint8_t* __restrict__ Aq,
                                                  const uint8_t* __restrict__ BqT,
                                                  float* __restrict__ C,
                                                  const float* __restrict__ sA,
                                                  const float* __restrict__ sB) {
  __shared__ __align__(16) uint8_t lds[131072];

  const int tid = threadIdx.x;
  const int lane = tid & 63;
  const int wid = tid >> 6;
  const int wr = wid >> 2;  // 0..1: 128-row strip of A
  const int wc = wid & 3;   // 0..3: 64-col strip of B
  const int l31 = lane & 31;
  const int hi2 = lane >> 5;  // 0..1

  // XCD-aware swizzle: 512 wgs, 64 per XCD chunk (bijective, 512%8==0)
  int bid = blockIdx.x;
  int wg = (bid & 7) * 64 + (bid >> 3);
  const long bm = (long)(wg >> 4) * 256;  // 32 M-tiles
  const long bn = (long)(wg & 15) * 256;  // 16 N-tiles

  // scales: materialize before staging so their loads never sit in the vmem
  // queue during the counted waits.
  float s = sA[0] * sB[0];
  asm volatile("" ::"v"(s));

  // --- staging: 2048 granules per matrix, 4 per thread, pre-swizzled src ---
  const uint8_t* gA[4];
  const uint8_t* gB[4];
  int ldo[4];
#pragma unroll
  for (int r = 0; r < 4; ++r) {
    int gid = tid + 512 * r;
    int row = gid >> 3, gc = gid & 7;
    int sc = (gc ^ (row & 7)) << 4;  // pre-swizzled source granule
    gA[r] = Aq + (bm + row) * (long)K_DIM + sc;
    gB[r] = BqT + (bn + row) * (long)K_DIM + sc;
    ldo[r] = gid * 16;  // linear LDS dest
  }

  // --- fragment read offsets (loop-invariant, swizzled) ---
  int offA[4][4], offB[2][4];
#pragma unroll
  for (int mi = 0; mi < 4; ++mi) {
    int ra = wr * 128 + mi * 32 + l31;  // 0..255
#pragma unroll
    for (int ks = 0; ks < 2; ++ks)
#pragma unroll
      for (int j = 0; j < 2; ++j) {
        int g = ks * 4 + hi2 * 2 + j;
        offA[mi][ks * 2 + j] = ra * 128 + ((g ^ (ra & 7)) << 4);
      }
  }
#pragma unroll
  for (int nj = 0; nj < 2; ++nj) {
    int rb = wc * 64 + nj * 32 + l31;  // 0..255
#pragma unroll
    for (int ks = 0; ks < 2; ++ks)
#pragma unroll
      for (int j = 0; j < 2; ++j) {
        int g = ks * 4 + hi2 * 2 + j;
        offB[nj][ks * 2 + j] = rb * 128 + ((g ^ (rb & 7)) << 4);
      }
  }

  f32x16 acc[4][2] = {};

  // ---- prologue ----
  stage_tile<0>(gA, gB, lds, ldo, 0);
  asm volatile("s_waitcnt vmcnt(0)" ::: "memory");
  __builtin_amdgcn_s_barrier();

  // ---- main loop: 2 K-tiles per iteration, static buffer indices ----
  for (int i = 0; i < NT / 2; ++i) {
    long ko1 = (long)((2 * i + 1) & (NT - 1)) * 128;
    stage_tile<1>(gA, gB, lds, ldo, ko1);   // issue first
    compute_tile<0>(lds, offA, offB, acc);  // 24 reads + 16 MFMA per wave
    asm volatile("s_waitcnt vmcnt(0)" ::: "memory");
    __builtin_amdgcn_s_barrier();

    long ko2 = (long)((2 * i + 2) & (NT - 1)) * 128;  // wraps harmlessly
    stage_tile<0>(gA, gB, lds, ldo, ko2);
    compute_tile<1>(lds, offA, offB, acc);
    asm volatile("s_waitcnt vmcnt(0)" ::: "memory");
    __builtin_amdgcn_s_barrier();
  }

  // ---- epilogue: C-write (32x32 C/D layout) ----
#pragma unroll
  for (int mi = 0; mi < 4; ++mi)
#pragma unroll
    for (int nj = 0; nj < 2; ++nj) {
      f32x16 v = acc[mi][nj];
      long col = bn + wc * 64 + nj * 32 + l31;
#pragma unroll
      for (int q = 0; q < 16; ++q) {
        long row = bm + wr * 128 + mi * 32 + (q & 3) + 8 * (q >> 2) + 4 * hi2;
        C[row * N_DIM + col] = v[q] * s;
      }
    }
}

// ---------- launcher ----------

extern "C" void kernel_launch(void* const* d_in, const int* in_sizes, int n_in,
                              void* d_out, int out_size, void* d_ws, size_t ws_size,
                              hipStream_t stream) {
  const float* A = (const float*)d_in[0];   // (8192, 4096)
  const float* B = (const float*)d_in[1];   // (4096, 4096)
  const float* sA = (const float*)d_in[2];  // input_scale
  const float* sB = (const float*)d_in[4];  // kernel_scale
  float* out = (float*)d_out;

  uint8_t* Aq = (uint8_t*)d_ws;               // M*K fp8
  uint8_t* BqT = Aq + (size_t)M_DIM * K_DIM;  // N*K fp8 (transposed)

  quant_fused<<<NA_BLK + NB_BLK, 256, 0, stream>>>(A, B, (u32*)Aq, BqT, sA, sB);
  gemm_mx<<<dim3((M_DIM / 256) * (N_DIM / 256)), 512, 0, stream>>>(Aq, BqT, out, sA, sB);
}